// Round 4
// baseline (78.740 us; speedup 1.0000x reference)
//
#include <hip/hip_runtime.h>

#define S1_BLOCKS 2048
#define S1_THREADS 256
#define WPB 4   // waves per block

// Stage 1: block-chunked, wave-private LDS transpose.
// Each block iteration covers 16 samples = 768 float4 per input. Each wave
// stages its own 192-float4 slice (4 samples) with perfectly coalesced
// global loads (lane i -> base+i, +64, +128 : 1024 B contiguous / instr),
// then reads its triplets back from LDS at 48 B stride (conflict-free for
// b128 reads: each 8-lane group covers all 32 banks once).
// __syncthreads() is used purely as a compiler/memory fence for the
// cross-LANE write->read dependency (per-wave regions are private, and the
// trip count is uniform across the block by construction).
__global__ __launch_bounds__(S1_THREADS) void mpjpe_stage1(
    const float4* __restrict__ pred4,
    const float4* __restrict__ gt4,
    float* __restrict__ partials,
    long long n_chunks,    // ceil(n_samples / 16)
    long long n4_total)    // total float4 elements per input
{
    __shared__ float4 sp[WPB][192];
    __shared__ float4 sg[WPB][192];

    int lane = threadIdx.x & 63;
    int wv   = threadIdx.x >> 6;

    float acc = 0.0f;
    for (long long c = blockIdx.x; c < n_chunks; c += gridDim.x) {
        long long base = c * 768 + (long long)wv * 192;
        bool full = (base + 192) <= n4_total;   // whole wave-slice in range

        if (full) {
            float4 P0 = pred4[base + lane];
            float4 P1 = pred4[base + 64 + lane];
            float4 P2 = pred4[base + 128 + lane];
            float4 G0 = gt4[base + lane];
            float4 G1 = gt4[base + 64 + lane];
            float4 G2 = gt4[base + 128 + lane];
            sp[wv][lane]       = P0;
            sp[wv][lane + 64]  = P1;
            sp[wv][lane + 128] = P2;
            sg[wv][lane]       = G0;
            sg[wv][lane + 64]  = G1;
            sg[wv][lane + 128] = G2;
        }
        __syncthreads();   // fence: LDS writes -> cross-lane reads

        if (full) {
            float4 p0 = sp[wv][lane * 3];
            float4 p1 = sp[wv][lane * 3 + 1];
            float4 p2 = sp[wv][lane * 3 + 2];
            float4 q0 = sg[wv][lane * 3];
            float4 q1 = sg[wv][lane * 3 + 1];
            float4 q2 = sg[wv][lane * 3 + 2];

            // triplet 0: joint (4*lane)&63 == 0 iff (lane&15)==0 -> masked
            float dx = p0.x - q0.x, dy = p0.y - q0.y, dz = p0.z - q0.z;
            float num = dx*dx + dy*dy + dz*dz;
            float den = q0.x*q0.x + q0.y*q0.y + q0.z*q0.z;
            float r0 = sqrtf(num / den);
            acc += ((lane & 15) == 0) ? 0.0f : r0;

            // triplet 1
            dx = p0.w - q0.w; dy = p1.x - q1.x; dz = p1.y - q1.y;
            num = dx*dx + dy*dy + dz*dz;
            den = q0.w*q0.w + q1.x*q1.x + q1.y*q1.y;
            acc += sqrtf(num / den);

            // triplet 2
            dx = p1.z - q1.z; dy = p1.w - q1.w; dz = p2.x - q2.x;
            num = dx*dx + dy*dy + dz*dz;
            den = q1.z*q1.z + q1.w*q1.w + q2.x*q2.x;
            acc += sqrtf(num / den);

            // triplet 3
            dx = p2.y - q2.y; dy = p2.z - q2.z; dz = p2.w - q2.w;
            num = dx*dx + dy*dy + dz*dz;
            den = q2.y*q2.y + q2.z*q2.z + q2.w*q2.w;
            acc += sqrtf(num / den);
        }
        __syncthreads();   // fence: reads done before next iter's writes (WAR)
    }

    // wave-64 reduce
    #pragma unroll
    for (int off = 32; off > 0; off >>= 1)
        acc += __shfl_down(acc, off, 64);

    __shared__ float wsum[WPB];
    if (lane == 0) wsum[wv] = acc;
    __syncthreads();

    if (threadIdx.x == 0) {
        float s = 0.0f;
        #pragma unroll
        for (int w = 0; w < WPB; ++w) s += wsum[w];
        partials[blockIdx.x] = s;
    }
}

// Stage 2: reduce S1_BLOCKS partials (double accum) -> mean scalar.
__global__ __launch_bounds__(256) void mpjpe_stage2(
    const float* __restrict__ partials,
    float* __restrict__ out,
    int n, double inv_count)
{
    double acc = 0.0;
    for (int i = threadIdx.x; i < n; i += blockDim.x)
        acc += (double)partials[i];

    #pragma unroll
    for (int off = 32; off > 0; off >>= 1)
        acc += __shfl_down(acc, off, 64);

    __shared__ double wsum[256 / 64];
    int lane = threadIdx.x & 63;
    int wave = threadIdx.x >> 6;
    if (lane == 0) wsum[wave] = acc;
    __syncthreads();

    if (threadIdx.x == 0) {
        double s = 0.0;
        #pragma unroll
        for (int w = 0; w < 256 / 64; ++w) s += wsum[w];
        out[0] = (float)(s * inv_count);
    }
}

extern "C" void kernel_launch(void* const* d_in, const int* in_sizes, int n_in,
                              void* d_out, int out_size, void* d_ws, size_t ws_size,
                              hipStream_t stream) {
    const float4* pred = (const float4*)d_in[0];
    const float4* gt   = (const float4*)d_in[1];
    float* out = (float*)d_out;
    float* partials = (float*)d_ws;

    long long n_samples = (long long)in_sizes[0] / 192;   // P=64, D=3
    long long n4_total  = n_samples * 48;                 // float4 per input
    long long n_chunks  = n_samples / 16;                 // 16 samples / chunk
    long long n_joints  = n_samples * 63;

    mpjpe_stage1<<<S1_BLOCKS, S1_THREADS, 0, stream>>>(pred, gt, partials,
                                                       n_chunks, n4_total);
    mpjpe_stage2<<<1, 256, 0, stream>>>(partials, out, S1_BLOCKS,
                                        1.0 / (double)n_joints);
}